// Round 10
// baseline (252.962 us; speedup 1.0000x reference)
//
#include <hip/hip_runtime.h>
#include <math.h>

// ComparingLoss: s = sum_{i<j, disc(i,j)} (d_i + d_j), out = s/T
// s = sum_i d_i * c_i, canonical predicate (xi>xj)^(li>lj) over ALL j.
//
// R10: ONE kernel, fence-free, init-free, EXACT last-arrival detection.
// All cross-block data moves through L3-executing atomic RMWs (returning
// forms), so nothing is ever stale and no wbl2/inv fences are needed:
//   member: atomicExch(partial[bid]) -> s_waitcnt vmcnt(0) -> +1 line ctr
//   leader (old==31, exact: ctrs maintained at 0): reset line, +1 C2
//   winner (old2==31): all 1024 exchanges transitively L3-complete ->
//     reduce via atomicAdd(p, 0.0f) reads, write out, reset C2.
// Counters self-reset to 0 each call => exactness is an invariant.
// Poisoned state (first call after harness 0xAA memset) is detected via a
// signature word: bid0 quiesces (counter sum stable over 64 polls), runs the
// identical reduce, then resets all counters + SIG. Every path is correct
// even if ws were re-poisoned at any point.

#define T_N  8192
#define BLK  256                  // threads per block
#define IPT  8                    // consecutive i-rows per thread
#define JC   32                   // j-chunk per block
#define NIB  (T_N / (BLK * IPT))  // 4 i-blocks
#define NJC  (T_N / JC)           // 256 j-chunks
#define NBLK (NIB * NJC)          // 1024 blocks
#define MAGIC 0x123456789ABCDEF0ULL

typedef unsigned long long ull;

__global__ __launch_bounds__(BLK) void pair_single_kernel(
    const float* __restrict__ x, const float* __restrict__ lab,
    ull* __restrict__ lines,   // 32 counters @128B stride (ws+0)
    ull* __restrict__ c2,      // ws+4096
    ull* __restrict__ sig,     // ws+4160
    float* __restrict__ partial,  // 1024 floats (ws+8192)
    float* __restrict__ out) {
  __shared__ float2 js[JC];
  __shared__ float wsum[BLK / 64];
  __shared__ double dsum[BLK / 64];
  __shared__ int do_red;

  const int tid = threadIdx.x;
  const int bid = blockIdx.y * NIB + blockIdx.x;
  const int i0 = blockIdx.x * (BLK * IPT) + tid * IPT;
  const int j0 = blockIdx.y * JC;

  if (tid < JC) js[tid] = make_float2(x[j0 + tid], lab[j0 + tid]);
  if (tid == 0) do_red = 0;

  const float4 xa = ((const float4*)&x[i0])[0];
  const float4 xb = ((const float4*)&x[i0])[1];
  const float4 la = ((const float4*)&lab[i0])[0];
  const float4 lb = ((const float4*)&lab[i0])[1];
  const float xi[IPT] = {xa.x, xa.y, xa.z, xa.w, xb.x, xb.y, xb.z, xb.w};
  const float li[IPT] = {la.x, la.y, la.z, la.w, lb.x, lb.y, lb.z, lb.w};
  __syncthreads();

  int cn[IPT] = {0, 0, 0, 0, 0, 0, 0, 0};
#pragma unroll 8
  for (int jj = 0; jj < JC; ++jj) {
    const float2 v = js[jj];  // broadcast ds_read_b64, conflict-free
#pragma unroll
    for (int k = 0; k < IPT; ++k)
      cn[k] += (int)((xi[k] > v.x) != (li[k] > v.y));
  }

  float val = 0.f;
#pragma unroll
  for (int k = 0; k < IPT; ++k)
    val += fabsf(xi[k] - li[k]) * (float)cn[k];

#pragma unroll
  for (int off = 32; off >= 1; off >>= 1) val += __shfl_down(val, off, 64);
  if ((tid & 63) == 0) wsum[tid >> 6] = val;
  __syncthreads();

  if (tid == 0) {
    const float s = wsum[0] + wsum[1] + wsum[2] + wsum[3];
    // publish via L3-executing returning atomic (never cached/stale)
    const float oldp = atomicExch(&partial[bid], s);
    __asm__ volatile("" ::"v"(oldp));                       // keep returning form
    __asm__ volatile("s_waitcnt vmcnt(0)" ::: "memory");    // exch done at L3
    const ull o1 = atomicAdd(&lines[(bid & 31) * 16], 1ULL);
    if (o1 == 31ULL) {                       // EXACT last of this line
      atomicAdd(&lines[(bid & 31) * 16], (ull)-32);  // reset line to 0
      const ull o2 = atomicAdd(c2, 1ULL);
      if (o2 == 31ULL) {                     // EXACT last line
        atomicAdd(c2, (ull)-32);             // reset C2 to 0
        do_red = 1;
      }
    }
    if (bid == 0) {                          // repair path (poisoned state)
      const ull sg = atomicAdd(sig, 0ULL);
      if (sg != MAGIC) {
        ull prev = ~0ULL;
        int stable = 0;
        while (stable < 64) {                // quiesce: sum stable 64 polls
          ull cur = atomicAdd(c2, 0ULL);
          for (int k = 0; k < 32; ++k) cur += atomicAdd(&lines[k * 16], 0ULL);
          if (cur == prev) ++stable; else { stable = 0; prev = cur; }
        }
        for (int k = 0; k < 32; ++k) atomicExch(&lines[k * 16], 0ULL);
        atomicExch(c2, 0ULL);
        atomicExch(sig, MAGIC);
        do_red = 1;
      }
    }
  }
  __syncthreads();  // broadcast do_red

  if (do_red) {
    const int base = tid * 4;
    double t = 0.0;
#pragma unroll
    for (int k = 0; k < 4; ++k) {
      const float v = atomicAdd(&partial[base + k], 0.0f);  // L3-fresh read
      t += (double)v;
    }
#pragma unroll
    for (int off = 32; off >= 1; off >>= 1) t += __shfl_down(t, off, 64);
    if ((tid & 63) == 0) dsum[tid >> 6] = t;
    __syncthreads();
    if (tid == 0)
      out[0] = (float)((dsum[0] + dsum[1] + dsum[2] + dsum[3]) / (double)T_N);
  }
}

extern "C" void kernel_launch(void* const* d_in, const int* in_sizes, int n_in,
                              void* d_out, int out_size, void* d_ws, size_t ws_size,
                              hipStream_t stream) {
  const float* x = (const float*)d_in[0];
  const float* lab = (const float*)d_in[1];
  float* out = (float*)d_out;
  ull* lines = (ull*)d_ws;                            // 32 @128B stride
  ull* c2 = (ull*)((char*)d_ws + 4096);
  ull* sig = (ull*)((char*)d_ws + 4160);
  float* partial = (float*)((char*)d_ws + 8192);      // 1024 floats

  dim3 grid(NIB, NJC);
  pair_single_kernel<<<grid, BLK, 0, stream>>>(x, lab, lines, c2, sig,
                                               partial, out);
}

// Round 11
// 14.796 us; speedup vs baseline: 17.0969x; 17.0969x over previous
//
#include <hip/hip_runtime.h>
#include <math.h>

// ComparingLoss: s = sum_{i<j, disc(i,j)} (d_i + d_j), out = s/T
// s = sum_i d_i * c_i, canonical predicate (xi>xj)^(li>lj) over ALL j
// (valid both orientations for tie-free data; false at j==i).
//
// R11 = R7 restored (best verified: 14.79us). Ledger of structure experiments:
//   two-node graph (this):        14.8 us   <- floor
//   one-node, steady-state (R10): ~15 us    (node count is NOT the cost)
//   one-node + memset node (R5):  18.8 us
//   one-node + flat atomic (R3):  27.2 us   (1024 same-addr RMW ~12ns each)
//   one-node + acq_rel fences(R9):25.4 us   (agent-scope wbl2/inv per RMW)
//   cooperative grid.sync (R6):   45.1 us   (~30us barrier)
// Cost model: ~10us fixed graph/harness floor + pair ~4.5us (VALU floor
// 2.6us: 67.1M preds x 3 VALU / 1024 SIMDs / 2 per cyc) + reduce ~1us.

#define T_N   8192
#define BLK   256                  // threads per block
#define IPT   8                    // consecutive i-rows per thread
#define JC    32                   // j-chunk per block
#define NIB   (T_N / (BLK * IPT))  // 4 i-blocks
#define NJC   (T_N / JC)           // 256 j-chunks
#define NPART (NIB * NJC)          // 1024 partials

__global__ __launch_bounds__(BLK) void pair_count_kernel(
    const float* __restrict__ x, const float* __restrict__ lab,
    float* __restrict__ partial) {
  __shared__ float2 js[JC];
  __shared__ float wsum[BLK / 64];

  const int tid = threadIdx.x;
  const int i0 = blockIdx.x * (BLK * IPT) + tid * IPT;  // 8 consecutive rows
  const int j0 = blockIdx.y * JC;

  if (tid < JC) js[tid] = make_float2(x[j0 + tid], lab[j0 + tid]);

  // 8 rows as 2x float4 (32B-aligned)
  const float4 xa = ((const float4*)&x[i0])[0];
  const float4 xb = ((const float4*)&x[i0])[1];
  const float4 la = ((const float4*)&lab[i0])[0];
  const float4 lb = ((const float4*)&lab[i0])[1];
  const float xi[IPT] = {xa.x, xa.y, xa.z, xa.w, xb.x, xb.y, xb.z, xb.w};
  const float li[IPT] = {la.x, la.y, la.z, la.w, lb.x, lb.y, lb.z, lb.w};
  __syncthreads();

  int cnt[IPT] = {0, 0, 0, 0, 0, 0, 0, 0};
#pragma unroll 8
  for (int jj = 0; jj < JC; ++jj) {
    const float2 v = js[jj];  // broadcast ds_read_b64, conflict-free
#pragma unroll
    for (int k = 0; k < IPT; ++k)
      cnt[k] += (int)((xi[k] > v.x) != (li[k] > v.y));
  }

  float val = 0.f;
#pragma unroll
  for (int k = 0; k < IPT; ++k)
    val += fabsf(xi[k] - li[k]) * (float)cnt[k];

  // wave-64 tree reduce
#pragma unroll
  for (int off = 32; off >= 1; off >>= 1) val += __shfl_down(val, off, 64);

  if ((tid & 63) == 0) wsum[tid >> 6] = val;
  __syncthreads();

  if (tid == 0) {
    const float s = wsum[0] + wsum[1] + wsum[2] + wsum[3];
    partial[blockIdx.y * NIB + blockIdx.x] = s;
  }
}

__global__ __launch_bounds__(64) void reduce_kernel(
    const float* __restrict__ partial, float* __restrict__ out) {
  const int tid = threadIdx.x;  // one wave, no __syncthreads needed
  // 4 independent float4 loads per lane cover 1024 partials
  const float4 p0 = ((const float4*)partial)[tid];
  const float4 p1 = ((const float4*)partial)[tid + 64];
  const float4 p2 = ((const float4*)partial)[tid + 128];
  const float4 p3 = ((const float4*)partial)[tid + 192];
  double s = ((double)p0.x + (double)p0.y + (double)p0.z + (double)p0.w) +
             ((double)p1.x + (double)p1.y + (double)p1.z + (double)p1.w) +
             ((double)p2.x + (double)p2.y + (double)p2.z + (double)p2.w) +
             ((double)p3.x + (double)p3.y + (double)p3.z + (double)p3.w);
#pragma unroll
  for (int off = 32; off >= 1; off >>= 1) s += __shfl_down(s, off, 64);
  if (tid == 0) out[0] = (float)(s / (double)T_N);
}

extern "C" void kernel_launch(void* const* d_in, const int* in_sizes, int n_in,
                              void* d_out, int out_size, void* d_ws, size_t ws_size,
                              hipStream_t stream) {
  const float* x = (const float*)d_in[0];
  const float* lab = (const float*)d_in[1];
  float* out = (float*)d_out;
  float* partial = (float*)d_ws;  // NPART floats = 4 KiB

  dim3 grid(NIB, NJC);
  pair_count_kernel<<<grid, BLK, 0, stream>>>(x, lab, partial);
  reduce_kernel<<<1, 64, 0, stream>>>(partial, out);
}